// Round 7
// baseline (108.027 us; speedup 1.0000x reference)
//
#include <hip/hip_runtime.h>

#define N_POINTS  131072
#define N_ANCHORS 2048
#define CHUNKS    64
#define M_PER     (N_ANCHORS / CHUNKS)   // 32 anchors per block
#define THREADS   256
#define PTS       4                      // points per thread
#define PT_STRIDE (N_POINTS / PTS)       // 32768
#define LOG2E     1.4426950408889634f

typedef float v2f __attribute__((ext_vector_type(2)));

// ---------------------------------------------------------------------------
// Grid (128, 64) x 256 = 8192 short blocks -> smooth CU packing (R5/R6: more,
// shorter blocks monotonically raised OccupancyPercent). Each block folds its
// 32-anchor chunk into LDS as DUPLICATED v2f pairs, then each thread runs
// 4 points x 32 anchors with a MANUAL 1-deep software pipeline on the LDS
// constant reads (R6 evidence: VGPR_Count=20 -> compiler did no cross-iter
// prefetch; each iter convoy-waited ~120cy LDS latency on lgkmcnt).
//   arg(n,m) = q + r.x_n + sp*|x_n|^2 ;  K = exp2(arg) ; out += cf*K
// ---------------------------------------------------------------------------
__global__ __launch_bounds__(256, 8) void linear_potential_main(
    const float* __restrict__ xloc,
    const float* __restrict__ aloc,
    const float* __restrict__ coeffs,
    const float* __restrict__ params,
    float* __restrict__ out)
{
    __shared__ v2f sA[M_PER][6];   // {r0,r1,r2,q,sp,cf} duplicated; 1.5 KiB

    const int t = threadIdx.x;

    if (t < M_PER) {
        const int m  = blockIdx.y * M_PER + t;
        const float a0 = aloc[3 * m + 0];
        const float a1 = aloc[3 * m + 1];
        const float a2 = aloc[3 * m + 2];
        const float w  = params[m];
        const float sp = -(0.5f * LOG2E) / (w * w);
        const float r0 = -2.0f * sp * a0;
        const float r1 = -2.0f * sp * a1;
        const float r2 = -2.0f * sp * a2;
        const float q  = sp * (a0 * a0 + a1 * a1 + a2 * a2);
        const float cf = coeffs[m];
        sA[t][0] = (v2f){r0, r0};
        sA[t][1] = (v2f){r1, r1};
        sA[t][2] = (v2f){r2, r2};
        sA[t][3] = (v2f){q,  q};
        sA[t][4] = (v2f){sp, sp};
        sA[t][5] = (v2f){cf, cf};
    }
    __syncthreads();

    const int tid = blockIdx.x * THREADS + t;     // [0, 32768)
    const int n0 = tid;
    const int n1 = tid + PT_STRIDE;
    const int n2 = tid + 2 * PT_STRIDE;
    const int n3 = tid + 3 * PT_STRIDE;

    const v2f xa = { xloc[3 * n0 + 0], xloc[3 * n1 + 0] };
    const v2f ya = { xloc[3 * n0 + 1], xloc[3 * n1 + 1] };
    const v2f za = { xloc[3 * n0 + 2], xloc[3 * n1 + 2] };
    const v2f xb = { xloc[3 * n2 + 0], xloc[3 * n3 + 0] };
    const v2f yb = { xloc[3 * n2 + 1], xloc[3 * n3 + 1] };
    const v2f zb = { xloc[3 * n2 + 2], xloc[3 * n3 + 2] };

    const v2f ssa = __builtin_elementwise_fma(xa, xa,
                    __builtin_elementwise_fma(ya, ya, za * za));
    const v2f ssb = __builtin_elementwise_fma(xb, xb,
                    __builtin_elementwise_fma(yb, yb, zb * zb));

    v2f acca = { 0.0f, 0.0f };
    v2f accb = { 0.0f, 0.0f };

    // ---- manual 1-deep pipeline over anchors (static buffer names) ----
    v2f A0 = sA[0][0], A1 = sA[0][1], A2 = sA[0][2],
        A3 = sA[0][3], A4 = sA[0][4], A5 = sA[0][5];
    v2f B0, B1, B2, B3, B4, B5;

#define BODY(c0, c1, c2, c3, c4, c5)                                   \
    do {                                                               \
        v2f arga = __builtin_elementwise_fma(c4, ssa, c3);             \
        arga     = __builtin_elementwise_fma(c0, xa, arga);            \
        arga     = __builtin_elementwise_fma(c1, ya, arga);            \
        arga     = __builtin_elementwise_fma(c2, za, arga);            \
        v2f argb = __builtin_elementwise_fma(c4, ssb, c3);             \
        argb     = __builtin_elementwise_fma(c0, xb, argb);            \
        argb     = __builtin_elementwise_fma(c1, yb, argb);            \
        argb     = __builtin_elementwise_fma(c2, zb, argb);            \
        v2f ea = { __builtin_amdgcn_exp2f(arga.x),                     \
                   __builtin_amdgcn_exp2f(arga.y) };                   \
        v2f eb = { __builtin_amdgcn_exp2f(argb.x),                     \
                   __builtin_amdgcn_exp2f(argb.y) };                   \
        acca = __builtin_elementwise_fma(c5, ea, acca);                \
        accb = __builtin_elementwise_fma(c5, eb, accb);                \
    } while (0)

    #pragma unroll 1
    for (int mm = 0; mm < M_PER; mm += 2) {
        // prefetch mm+1 into B while computing A
        B0 = sA[mm + 1][0]; B1 = sA[mm + 1][1]; B2 = sA[mm + 1][2];
        B3 = sA[mm + 1][3]; B4 = sA[mm + 1][4]; B5 = sA[mm + 1][5];
        BODY(A0, A1, A2, A3, A4, A5);
        if (mm + 2 < M_PER) {
            A0 = sA[mm + 2][0]; A1 = sA[mm + 2][1]; A2 = sA[mm + 2][2];
            A3 = sA[mm + 2][3]; A4 = sA[mm + 2][4]; A5 = sA[mm + 2][5];
        }
        BODY(B0, B1, B2, B3, B4, B5);
    }
#undef BODY

    atomicAdd(&out[n0], acca.x);
    atomicAdd(&out[n1], acca.y);
    atomicAdd(&out[n2], accb.x);
    atomicAdd(&out[n3], accb.y);
}

extern "C" void kernel_launch(void* const* d_in, const int* in_sizes, int n_in,
                              void* d_out, int out_size, void* d_ws, size_t ws_size,
                              hipStream_t stream) {
    const float* xloc   = (const float*)d_in[0];   // [131072,3]
    const float* aloc   = (const float*)d_in[1];   // [2048,3]
    const float* coeffs = (const float*)d_in[2];   // [2048]
    const float* params = (const float*)d_in[3];   // [2048]
    float* out = (float*)d_out;                    // [131072] f32

    // d_out is poisoned 0xAA before every timed call -> zero it (capturable).
    hipMemsetAsync(d_out, 0, N_POINTS * sizeof(float), stream);

    linear_potential_main<<<dim3(N_POINTS / (THREADS * PTS), CHUNKS),
                            dim3(THREADS), 0, stream>>>(
        xloc, aloc, coeffs, params, out);
}

// Round 8
// 97.792 us; speedup vs baseline: 1.1047x; 1.1047x over previous
//
#include <hip/hip_runtime.h>

#define N_POINTS  131072
#define N_ANCHORS 2048
#define CHUNKS    32
#define M_PER     (N_ANCHORS / CHUNKS)   // 64 anchors per block
#define THREADS   256
#define PTS       8                      // points per thread
#define PT_STRIDE (N_POINTS / PTS)       // 16384
#define LOG2E     1.4426950408889634f

typedef float v2f __attribute__((ext_vector_type(2)));

// ---------------------------------------------------------------------------
// Grid (64, 32) x 256 = 2048 blocks = EXACTLY one co-resident round
// (8 blocks/CU x 4 waves = 32 waves/CU) -- no multi-round ramp/drain idle.
// Each block folds its 64-anchor chunk into LDS (duplicated v2f pairs,
// uniform-address ds_read_b64 broadcast -> all-VGPR pk_fma sources).
// 8 points/thread = 4 independent v2f chains + 8 independent exps per iter:
// maximal ILP for the scheduler to overlap trans-pipe exp with main-pipe FMA
// (this round is the overlap probe -- R5/R7 taught us: NO hand-scheduling).
//   arg(n,m) = q + r.x_n + sp*|x_n|^2 ;  K = exp2(arg) ; out += cf*K
// ---------------------------------------------------------------------------
__global__ __launch_bounds__(256, 8) void linear_potential_main(
    const float* __restrict__ xloc,
    const float* __restrict__ aloc,
    const float* __restrict__ coeffs,
    const float* __restrict__ params,
    float* __restrict__ out)
{
    __shared__ v2f sA[M_PER][6];   // {r0,r1,r2,q,sp,cf} duplicated; 3 KiB

    const int t = threadIdx.x;

    if (t < M_PER) {
        const int m  = blockIdx.y * M_PER + t;
        const float a0 = aloc[3 * m + 0];
        const float a1 = aloc[3 * m + 1];
        const float a2 = aloc[3 * m + 2];
        const float w  = params[m];
        const float sp = -(0.5f * LOG2E) / (w * w);
        const float r0 = -2.0f * sp * a0;
        const float r1 = -2.0f * sp * a1;
        const float r2 = -2.0f * sp * a2;
        const float q  = sp * (a0 * a0 + a1 * a1 + a2 * a2);
        const float cf = coeffs[m];
        sA[t][0] = (v2f){r0, r0};
        sA[t][1] = (v2f){r1, r1};
        sA[t][2] = (v2f){r2, r2};
        sA[t][3] = (v2f){q,  q};
        sA[t][4] = (v2f){sp, sp};
        sA[t][5] = (v2f){cf, cf};
    }
    __syncthreads();

    const int tid = blockIdx.x * THREADS + t;     // [0, 16384)
    const int n0 = tid;
    const int n1 = tid + PT_STRIDE;
    const int n2 = tid + 2 * PT_STRIDE;
    const int n3 = tid + 3 * PT_STRIDE;
    const int n4 = tid + 4 * PT_STRIDE;
    const int n5 = tid + 5 * PT_STRIDE;
    const int n6 = tid + 6 * PT_STRIDE;
    const int n7 = tid + 7 * PT_STRIDE;

    const v2f xa = { xloc[3 * n0 + 0], xloc[3 * n1 + 0] };
    const v2f ya = { xloc[3 * n0 + 1], xloc[3 * n1 + 1] };
    const v2f za = { xloc[3 * n0 + 2], xloc[3 * n1 + 2] };
    const v2f xb = { xloc[3 * n2 + 0], xloc[3 * n3 + 0] };
    const v2f yb = { xloc[3 * n2 + 1], xloc[3 * n3 + 1] };
    const v2f zb = { xloc[3 * n2 + 2], xloc[3 * n3 + 2] };
    const v2f xc = { xloc[3 * n4 + 0], xloc[3 * n5 + 0] };
    const v2f yc = { xloc[3 * n4 + 1], xloc[3 * n5 + 1] };
    const v2f zc = { xloc[3 * n4 + 2], xloc[3 * n5 + 2] };
    const v2f xd = { xloc[3 * n6 + 0], xloc[3 * n7 + 0] };
    const v2f yd = { xloc[3 * n6 + 1], xloc[3 * n7 + 1] };
    const v2f zd = { xloc[3 * n6 + 2], xloc[3 * n7 + 2] };

    const v2f ssa = __builtin_elementwise_fma(xa, xa,
                    __builtin_elementwise_fma(ya, ya, za * za));
    const v2f ssb = __builtin_elementwise_fma(xb, xb,
                    __builtin_elementwise_fma(yb, yb, zb * zb));
    const v2f ssc = __builtin_elementwise_fma(xc, xc,
                    __builtin_elementwise_fma(yc, yc, zc * zc));
    const v2f ssd = __builtin_elementwise_fma(xd, xd,
                    __builtin_elementwise_fma(yd, yd, zd * zd));

    v2f acca = { 0.0f, 0.0f };
    v2f accb = { 0.0f, 0.0f };
    v2f accc = { 0.0f, 0.0f };
    v2f accd = { 0.0f, 0.0f };

    #pragma unroll 2
    for (int mm = 0; mm < M_PER; ++mm) {
        const v2f r0 = sA[mm][0];
        const v2f r1 = sA[mm][1];
        const v2f r2 = sA[mm][2];
        const v2f q  = sA[mm][3];
        const v2f sp = sA[mm][4];
        const v2f cf = sA[mm][5];

        v2f arga = __builtin_elementwise_fma(sp, ssa, q);
        v2f argb = __builtin_elementwise_fma(sp, ssb, q);
        v2f argc = __builtin_elementwise_fma(sp, ssc, q);
        v2f argd = __builtin_elementwise_fma(sp, ssd, q);

        arga = __builtin_elementwise_fma(r0, xa, arga);
        argb = __builtin_elementwise_fma(r0, xb, argb);
        argc = __builtin_elementwise_fma(r0, xc, argc);
        argd = __builtin_elementwise_fma(r0, xd, argd);

        arga = __builtin_elementwise_fma(r1, ya, arga);
        argb = __builtin_elementwise_fma(r1, yb, argb);
        argc = __builtin_elementwise_fma(r1, yc, argc);
        argd = __builtin_elementwise_fma(r1, yd, argd);

        arga = __builtin_elementwise_fma(r2, za, arga);
        argb = __builtin_elementwise_fma(r2, zb, argb);
        argc = __builtin_elementwise_fma(r2, zc, argc);
        argd = __builtin_elementwise_fma(r2, zd, argd);

        v2f ea = { __builtin_amdgcn_exp2f(arga.x), __builtin_amdgcn_exp2f(arga.y) };
        v2f eb = { __builtin_amdgcn_exp2f(argb.x), __builtin_amdgcn_exp2f(argb.y) };
        v2f ec = { __builtin_amdgcn_exp2f(argc.x), __builtin_amdgcn_exp2f(argc.y) };
        v2f ed = { __builtin_amdgcn_exp2f(argd.x), __builtin_amdgcn_exp2f(argd.y) };

        acca = __builtin_elementwise_fma(cf, ea, acca);
        accb = __builtin_elementwise_fma(cf, eb, accb);
        accc = __builtin_elementwise_fma(cf, ec, accc);
        accd = __builtin_elementwise_fma(cf, ed, accd);
    }

    atomicAdd(&out[n0], acca.x);
    atomicAdd(&out[n1], acca.y);
    atomicAdd(&out[n2], accb.x);
    atomicAdd(&out[n3], accb.y);
    atomicAdd(&out[n4], accc.x);
    atomicAdd(&out[n5], accc.y);
    atomicAdd(&out[n6], accd.x);
    atomicAdd(&out[n7], accd.y);
}

extern "C" void kernel_launch(void* const* d_in, const int* in_sizes, int n_in,
                              void* d_out, int out_size, void* d_ws, size_t ws_size,
                              hipStream_t stream) {
    const float* xloc   = (const float*)d_in[0];   // [131072,3]
    const float* aloc   = (const float*)d_in[1];   // [2048,3]
    const float* coeffs = (const float*)d_in[2];   // [2048]
    const float* params = (const float*)d_in[3];   // [2048]
    float* out = (float*)d_out;                    // [131072] f32

    // d_out is poisoned 0xAA before every timed call -> zero it (capturable).
    hipMemsetAsync(d_out, 0, N_POINTS * sizeof(float), stream);

    linear_potential_main<<<dim3(N_POINTS / (THREADS * PTS), CHUNKS),
                            dim3(THREADS), 0, stream>>>(
        xloc, aloc, coeffs, params, out);
}

// Round 9
// 92.406 us; speedup vs baseline: 1.1690x; 1.0583x over previous
//
#include <hip/hip_runtime.h>

#define N_POINTS  131072
#define N_ANCHORS 2048
#define THREADS   256
#define PTS_BLK   128                       // points per block
#define NBLOCKS   (N_POINTS / PTS_BLK)      // 1024
#define NTILES_M  (N_ANCHORS / 16)          // 128 anchor tiles of 16
#define LOG2E     1.4426950408889634f

typedef __attribute__((ext_vector_type(8))) short  short8;   // 8 bf16 = MFMA A/B frag
typedef __attribute__((ext_vector_type(4))) float  f32x4;    // MFMA C/D frag

// ---------------------------------------------------------------------------
// Split-GEMM formulation:  arg(n,m) = q_m + r_m.x_n + sp_m*|x_n|^2  computed
// by mfma_f32_16x16x32_bf16 with each f32 quantity split into 3 bf16 limbs
// (RNE; residual 2^-27 rel). K-slot plan (27 of 32 used), product pairs per
// group = (1,1),(1,2),(2,1),(1,3),(3,1),(2,2) -> residual ~2^-27*|P|:
//   s0-5 : x * r0     s6-11: y * r1     s12-17: z * r2
//   s18-23: ss * sp   s24-26: 1 * q(1..3)   s27-31: zero
// A-side (points): lane&15 = point row, lane>>4 = k-group, 8 slots each.
// B-side (anchors): lane&15 = anchor col, same k-grouping.
// C/D: col = lane&15 (anchor), row = (lane>>4)*4 + reg (point)  [m89-verified].
// VALU keeps only exp2 + accumulate; the 5 FMAs/pair move to the MFMA pipe
// (separate pipe, m114) -> predicted VALU busy halves vs R6/R8.
// ---------------------------------------------------------------------------

static __device__ __forceinline__ unsigned short f2bf(float v) {
    union { float f; unsigned u; } c; c.f = v;
    unsigned r = (c.u + 0x7FFFu + ((c.u >> 16) & 1u)) >> 16;   // RNE
    return (unsigned short)r;
}
static __device__ __forceinline__ float bf2f(unsigned short h) {
    union { unsigned u; float f; } c; c.u = ((unsigned)h) << 16;
    return c.f;
}
static __device__ __forceinline__ void split3(float v, unsigned short& h1,
                                              unsigned short& h2, unsigned short& h3) {
    h1 = f2bf(v); float v2 = v - bf2f(h1);
    h2 = f2bf(v2); float v3 = v2 - bf2f(h2);
    h3 = f2bf(v3);
}

#define BF_ONE ((short)0x3F80)

// ---------------------------------------------------------------------------
// prep_B: build the anchor-side fragment matrix in ws.
// Bws[tile][lane] = short8 of this lane's 8 k-slot bf16 values.
// One thread per (tile,lane) = 8192 threads. lanes 0-15 also write cf.
// ---------------------------------------------------------------------------
__global__ void prep_B(const float* __restrict__ aloc,
                       const float* __restrict__ coeffs,
                       const float* __restrict__ params,
                       short8* __restrict__ Bws,
                       float* __restrict__ cfws) {
    const int gid  = blockIdx.x * blockDim.x + threadIdx.x;   // [0, 8192)
    const int tile = gid >> 6;
    const int lane = gid & 63;
    const int kb   = lane >> 4;
    const int m    = tile * 16 + (lane & 15);

    const float a0 = aloc[3 * m + 0];
    const float a1 = aloc[3 * m + 1];
    const float a2 = aloc[3 * m + 2];
    const float w  = params[m];
    const float sp = -(0.5f * LOG2E) / (w * w);
    const float r0 = -2.0f * sp * a0;
    const float r1 = -2.0f * sp * a1;
    const float r2 = -2.0f * sp * a2;
    const float q  = sp * (a0 * a0 + a1 * a1 + a2 * a2);

    unsigned short r0a, r0b, r0c, r1a, r1b, r1c, r2a, r2b, r2c, spa, spb, spc, qa, qb, qc;
    split3(r0, r0a, r0b, r0c);
    split3(r1, r1a, r1b, r1c);
    split3(r2, r2a, r2b, r2c);
    split3(sp, spa, spb, spc);
    split3(q,  qa,  qb,  qc);

    short8 fr;
    switch (kb) {   // B-side limb pattern per group: {1,2,1,3,1,2}
    case 0: fr = (short8){(short)r0a,(short)r0b,(short)r0a,(short)r0c,(short)r0a,(short)r0b,(short)r1a,(short)r1b}; break;
    case 1: fr = (short8){(short)r1a,(short)r1c,(short)r1a,(short)r1b,(short)r2a,(short)r2b,(short)r2a,(short)r2c}; break;
    case 2: fr = (short8){(short)r2a,(short)r2b,(short)spa,(short)spb,(short)spa,(short)spc,(short)spa,(short)spb}; break;
    default:fr = (short8){(short)qa, (short)qb, (short)qc, 0, 0, 0, 0, 0}; break;
    }
    Bws[tile * 64 + lane] = fr;

    if (lane < 16) cfws[m] = coeffs[m];
}

// ---------------------------------------------------------------------------
// Main: 1024 blocks x 256 thr (4 waves). Block owns 128 points x ALL anchors
// -> direct stores, no atomics, no memset. Per wave: 2 A-frags (32 points),
// loop 128 anchor tiles: 2 MFMA + 8 exp2 + 8 fma.
// ---------------------------------------------------------------------------
__global__ __launch_bounds__(256, 4) void lp_main(
    const float* __restrict__ xloc,
    const short8* __restrict__ Bws,
    const float* __restrict__ cfws,
    float* __restrict__ out)
{
    __shared__ short8 sA[8][64];     // 8 point-tiles of 16 x 64 lanes, 8 KiB

    const int t = threadIdx.x;

    // ---- stage this block's 128 points as A-fragments (512 entries) ----
    #pragma unroll
    for (int e0 = 0; e0 < 2; ++e0) {
        const int e    = t + e0 * 256;
        const int tl   = e >> 6;
        const int lane = e & 63;
        const int kb   = lane >> 4;
        const int p    = blockIdx.x * PTS_BLK + tl * 16 + (lane & 15);

        const float x = xloc[3 * p + 0];
        const float y = xloc[3 * p + 1];
        const float z = xloc[3 * p + 2];
        const float ss = fmaf(x, x, fmaf(y, y, z * z));

        unsigned short xa, xb, xc, ya, yb, yc, za, zb, zc, sa, sb, sc;
        split3(x,  xa, xb, xc);
        split3(y,  ya, yb, yc);
        split3(z,  za, zb, zc);
        split3(ss, sa, sb, sc);

        short8 fr;
        switch (kb) {   // A-side limb pattern per group: {1,1,2,1,3,2}
        case 0: fr = (short8){(short)xa,(short)xa,(short)xb,(short)xa,(short)xc,(short)xb,(short)ya,(short)ya}; break;
        case 1: fr = (short8){(short)yb,(short)ya,(short)yc,(short)yb,(short)za,(short)za,(short)zb,(short)za}; break;
        case 2: fr = (short8){(short)zc,(short)zb,(short)sa,(short)sa,(short)sb,(short)sa,(short)sc,(short)sb}; break;
        default:fr = (short8){BF_ONE, BF_ONE, BF_ONE, 0, 0, 0, 0, 0}; break;
        }
        sA[tl][lane] = fr;
    }
    __syncthreads();

    const int wave = t >> 6;
    const int lane = t & 63;
    const int col  = lane & 15;

    const short8 a0 = sA[wave * 2 + 0][lane];
    const short8 a1 = sA[wave * 2 + 1][lane];

    f32x4 acc0 = {0.f, 0.f, 0.f, 0.f};
    f32x4 acc1 = {0.f, 0.f, 0.f, 0.f};
    const f32x4 cz = {0.f, 0.f, 0.f, 0.f};

    #pragma unroll 2
    for (int tm = 0; tm < NTILES_M; ++tm) {
        const short8 bf = Bws[tm * 64 + lane];
        const float  cf = cfws[tm * 16 + col];

        f32x4 c0 = __builtin_amdgcn_mfma_f32_16x16x32_bf16(a0, bf, cz, 0, 0, 0);
        f32x4 c1 = __builtin_amdgcn_mfma_f32_16x16x32_bf16(a1, bf, cz, 0, 0, 0);

        #pragma unroll
        for (int r = 0; r < 4; ++r) {
            acc0[r] = fmaf(cf, __builtin_amdgcn_exp2f(c0[r]), acc0[r]);
            acc1[r] = fmaf(cf, __builtin_amdgcn_exp2f(c1[r]), acc1[r]);
        }
    }

    // ---- reduce over the 16 anchor-col lanes of each group ----
    #pragma unroll
    for (int o = 1; o < 16; o <<= 1) {
        #pragma unroll
        for (int r = 0; r < 4; ++r) {
            acc0[r] += __shfl_xor(acc0[r], o, 16);
            acc1[r] += __shfl_xor(acc1[r], o, 16);
        }
    }

    if (col == 0) {
        const int kb = lane >> 4;
        const int pb = blockIdx.x * PTS_BLK + wave * 32;
        #pragma unroll
        for (int r = 0; r < 4; ++r) {
            out[pb +      kb * 4 + r] = acc0[r];
            out[pb + 16 + kb * 4 + r] = acc1[r];
        }
    }
}

extern "C" void kernel_launch(void* const* d_in, const int* in_sizes, int n_in,
                              void* d_out, int out_size, void* d_ws, size_t ws_size,
                              hipStream_t stream) {
    const float* xloc   = (const float*)d_in[0];   // [131072,3]
    const float* aloc   = (const float*)d_in[1];   // [2048,3]
    const float* coeffs = (const float*)d_in[2];   // [2048]
    const float* params = (const float*)d_in[3];   // [2048]
    float* out = (float*)d_out;                    // [131072] f32

    short8* Bws = (short8*)d_ws;                                   // 128 KiB
    float*  cfws = (float*)((char*)d_ws + NTILES_M * 64 * sizeof(short8)); // +8 KiB

    prep_B<<<dim3((NTILES_M * 64) / THREADS), dim3(THREADS), 0, stream>>>(
        aloc, coeffs, params, Bws, cfws);

    lp_main<<<dim3(NBLOCKS), dim3(THREADS), 0, stream>>>(
        xloc, Bws, cfws, out);
}